// Round 7
// baseline (1832.599 us; speedup 1.0000x reference)
//
#include <hip/hip_runtime.h>
#include <math.h>

#define NN 325
#define NPAD 352     // n padded (32-mult)
#define KPAD 352     // node dim padded for K loop
#define BBv 128
#define TTv 12
#define HHv 128
#define DFDv 32
#define ODDv 2
#define G3v 384
#define GX 11
#define GY 64

typedef __attribute__((ext_vector_type(8))) short bf16x8;
typedef __attribute__((ext_vector_type(4))) float f32x4;
typedef __attribute__((ext_vector_type(8))) unsigned short ushort8;
typedef unsigned short ushort;

__device__ __forceinline__ ushort f2bf(float f) {
    union { float f; unsigned u; } v; v.f = f;
    unsigned r = v.u + 0x7FFFu + ((v.u >> 16) & 1u);
    return (ushort)(r >> 16);
}
__device__ __forceinline__ float bf2f(ushort u) {
    union { unsigned u; float f; } v; v.u = ((unsigned)u) << 16; return v.f;
}
__device__ __forceinline__ float sigmoidf_(float x) { return 1.0f / (1.0f + __expf(-x)); }

#define MFMA(a,b,c) __builtin_amdgcn_mfma_f32_16x16x32_bf16((a),(b),(c),0,0,0)

// ---------------------------------------------------------------------------
// setup kernels (once per launch)
// ---------------------------------------------------------------------------
__global__ void wtrans_kernel(const float* __restrict__ W, ushort* __restrict__ Wt,
                              int K, int N, int KP) {
    int idx = blockIdx.x * 256 + threadIdx.x;
    if (idx >= N * KP) return;
    int n = idx / KP, k = idx - n * KP;
    Wt[idx] = f2bf(k < K ? W[(size_t)k * N + n] : 0.f);
}
// Wx0 permuted: k<32 -> feat rows (4+k); k in [32,36) -> data rows (k-32); else 0
__global__ void wtransx0_kernel(const float* __restrict__ W, ushort* __restrict__ Wt) {
    int idx = blockIdx.x * 256 + threadIdx.x;
    if (idx >= G3v * 64) return;
    int n = idx / 64, k = idx - n * 64;
    int src = (k < 32) ? (4 + k) : ((k < 36) ? (k - 32) : -1);
    Wt[idx] = f2bf(src >= 0 ? W[(size_t)src * G3v + n] : 0.f);
}
__global__ void aconv_kernel(const float* __restrict__ A, ushort* __restrict__ Ab) {
    int idx = blockIdx.x * 256 + threadIdx.x;
    if (idx >= NPAD * KPAD) return;
    int n = idx / KPAD, m = idx - n * KPAD;
    Ab[idx] = f2bf((n < NN && m < NN) ? A[n * NN + m] : 0.f);
}
__global__ void fconv_kernel(const float* __restrict__ F, ushort* __restrict__ Fb) {
    int idx = blockIdx.x * 256 + threadIdx.x;
    if (idx >= NPAD * DFDv) return;
    int n = idx >> 5, c = idx & 31;
    Fb[idx] = f2bf(n < NN ? F[n * DFDv + c] : 0.f);
}
// state fp32 [n][b][ch] -> transposed bf16 xt[(b*128+ch)][node]
__global__ void strans_kernel(const float* __restrict__ S, ushort* __restrict__ xt) {
    int idx = blockIdx.x * 256 + threadIdx.x;
    if (idx >= BBv * HHv * KPAD) return;
    int col = idx / KPAD, n = idx - col * KPAD;
    int b = col >> 7, ch = col & 127;
    xt[idx] = (n < NN) ? f2bf(S[((size_t)n * BBv + b) * HHv + ch]) : (ushort)0;
}
// gxf0[n][j] = bias[j] + sum_k feat[n][k] * Wx0[(4+k)*384 + j]   (fp32, prologue only)
__global__ void gxf_kernel(const float* __restrict__ W, const float* __restrict__ bias,
                           const float* __restrict__ feat, float* __restrict__ gxf, int row0) {
    int n = blockIdx.x, j = threadIdx.x;
    int nc = (n < NN) ? n : NN - 1;
    float a = bias[j];
    #pragma unroll 8
    for (int k = 0; k < DFDv; ++k) a = fmaf(feat[nc * DFDv + k], W[(size_t)(row0 + k) * G3v + j], a);
    gxf[(size_t)n * G3v + j] = a;
}
// pfeat[n][c] = bp[c] + sum_k feat[n][k] * Wp[(128+k)*2 + c]
__global__ void pfeat_kernel(const float* __restrict__ Wp, const float* __restrict__ bp,
                             const float* __restrict__ feat, float* __restrict__ pf) {
    int n = blockIdx.x, c = threadIdx.x;
    if (c >= 2) return;
    int nc = (n < NN) ? n : NN - 1;
    float a = bp[c];
    #pragma unroll 8
    for (int k = 0; k < DFDv; ++k) a = fmaf(feat[nc * DFDv + k], Wp[(size_t)(HHv + k) * ODDv + c], a);
    pf[n * 2 + c] = a;
}

// ---------------------------------------------------------------------------
// Prologue GRU0 at t=0: x-data = 0, so g_x = gxf0 (fp32, incl bias+feat part).
// ---------------------------------------------------------------------------
__global__ __launch_bounds__(512) void gru0_init(
    const float* __restrict__ state0,
    const float* __restrict__ gxf0,
    const ushort* __restrict__ Wht,
    ushort* __restrict__ xt)
{
    __shared__ ushort hs[32][136];
    __shared__ ushort hnb[32][136];
    const int n0 = blockIdx.x * 32;
    const int b  = blockIdx.y;
    const int tid = threadIdx.x;
    {
        int i = tid >> 4, c0 = (tid & 15) * 8;
        int n = n0 + i; if (n > NN - 1) n = NN - 1;
        const float* src = state0 + ((size_t)(n * BBv + b) * HHv + c0);
        float4 v0 = *(const float4*)src;
        float4 v1 = *(const float4*)(src + 4);
        ushort* dst = &hs[i][c0];
        dst[0]=f2bf(v0.x); dst[1]=f2bf(v0.y); dst[2]=f2bf(v0.z); dst[3]=f2bf(v0.w);
        dst[4]=f2bf(v1.x); dst[5]=f2bf(v1.y); dst[6]=f2bf(v1.z); dst[7]=f2bf(v1.w);
    }
    __syncthreads();

    const int w = tid >> 6, l = tid & 63, lr = l & 15, lk = l >> 4;
    const int ch = w * 16 + lr;

    f32x4 az[2], ar[2], agc[2], ahc[2];
    #pragma unroll
    for (int rt = 0; rt < 2; ++rt)
        #pragma unroll
        for (int i = 0; i < 4; ++i) {
            int nl = rt * 16 + lk * 4 + i;
            const float* g = gxf0 + (size_t)(n0 + nl) * G3v;
            az[rt][i]  = g[ch];
            ar[rt][i]  = g[128 + ch];
            agc[rt][i] = g[256 + ch];
            ahc[rt][i] = 0.f;
        }
    #pragma unroll
    for (int kk = 0; kk < 4; ++kk) {
        const int kb = kk * 32 + lk * 8;
        bf16x8 bz = *(const bf16x8*)(Wht + (size_t)(ch) * HHv + kb);
        bf16x8 br = *(const bf16x8*)(Wht + (size_t)(128 + ch) * HHv + kb);
        bf16x8 bc = *(const bf16x8*)(Wht + (size_t)(256 + ch) * HHv + kb);
        #pragma unroll
        for (int rt = 0; rt < 2; ++rt) {
            bf16x8 a = *(const bf16x8*)&hs[rt * 16 + lr][kb];
            az[rt] = MFMA(a, bz, az[rt]);
            ar[rt] = MFMA(a, br, ar[rt]);
            ahc[rt] = MFMA(a, bc, ahc[rt]);
        }
    }
    #pragma unroll
    for (int rt = 0; rt < 2; ++rt)
        #pragma unroll
        for (int i = 0; i < 4; ++i) {
            int r2 = rt * 16 + lk * 4 + i;
            float z  = sigmoidf_(az[rt][i]);
            float rr = sigmoidf_(ar[rt][i]);
            float c  = tanhf(agc[rt][i] + rr * ahc[rt][i]);
            float hn = z * bf2f(hs[r2][ch]) + (1.f - z) * c;
            hnb[r2][ch] = f2bf(hn);
        }
    __syncthreads();
    {
        int chx = tid >> 2, g = tid & 3;
        ushort8 v;
        #pragma unroll
        for (int k = 0; k < 8; ++k) v[k] = hnb[g * 8 + k][chx];
        *(ushort8*)(xt + (size_t)(b * HHv + chx) * KPAD + n0 + g * 8) = v;
    }
}

// ---------------------------------------------------------------------------
// Fused step kernel. 32 nodes x 2 batches (64 rows), 512 threads = 8 waves.
// WHICH=0 (K_A): gconv0(h0[t]) -> d -> GRU1(x=[d|feat],K=160) -> h1[t]
// WHICH=1 (K_B): gconv1(h1[t]) -> d -> proj out[t] -> GRU0(x=[feat|out,aux],K=64) -> h0[t+1]
// LDS: m1s+m2s+hs+fs ~53KB -> 3 blocks/CU; launch_bounds(512,6) caps VGPR.
// ---------------------------------------------------------------------------
template<int WHICH>
__global__ __launch_bounds__(512, 6) void fused_step(
    const ushort* __restrict__ xtB,
    const ushort* __restrict__ xtH,
    ushort* __restrict__ xtO,
    const ushort* __restrict__ Ab1,
    const ushort* __restrict__ Ab2,
    const ushort* __restrict__ W1t,
    const ushort* __restrict__ W2t,
    const ushort* __restrict__ Wxt,     // [384][KXP]
    const ushort* __restrict__ Wht,     // [384][128]
    const float* __restrict__ bias,     // [384]
    const ushort* __restrict__ featb,   // [352][32] bf16
    const float* __restrict__ label,
    const float* __restrict__ Wp,
    const float* __restrict__ pfeat,    // [352][2]
    float* __restrict__ out,
    int t)
{
    constexpr int KXP = (WHICH == 0) ? 160 : 64;
    __shared__ ushort m1s[64][136];     // GEMM1 out1 / d / (os in cols 128..131)
    __shared__ ushort m2s[64][136];     // GEMM1 out2 / xs (WHICH=1) / h-new
    __shared__ ushort hs[64][136];      // h-old
    __shared__ ushort fs[32][32];       // feat tile bf16

    // XCD-aware swizzle (bijective: 704 = 8 XCD x 88)
    int rid = blockIdx.x + GX * blockIdx.y;
    int xcd = rid & 7, rank = rid >> 3;
    int qy = rank / GX;
    const int n0 = (rank - qy * GX) * 32;
    const int b0 = (xcd * 8 + qy) * 2;

    const int tid = threadIdx.x;
    const int w = tid >> 6, l = tid & 63, lr = l & 15, lk = l >> 4;

    // ---- stage h-old (transpose from xtH) + feat tile ----
    {
        int chg = tid >> 1, g = tid & 1;
        int bl = chg >> 7, ch = chg & 127;
        const ushort* src = xtH + (size_t)((b0 + bl) * HHv + ch) * KPAD + n0 + g * 16;
        ushort8 v0 = *(const ushort8*)src;
        ushort8 v1 = *(const ushort8*)(src + 8);
        #pragma unroll
        for (int k = 0; k < 8; ++k) hs[bl * 32 + g * 16 + k][ch] = v0[k];
        #pragma unroll
        for (int k = 0; k < 8; ++k) hs[bl * 32 + g * 16 + 8 + k][ch] = v1[k];
    }
    if (tid < 128) {
        int nl = tid >> 2, c0 = (tid & 3) * 8;
        *(ushort8*)&fs[nl][c0] = *(const ushort8*)(featb + (n0 + nl) * DFDv + c0);
    }

    // ---- GEMM1: m = A*X, 32 n-rows x 256 cols, K=352 ----
    f32x4 m1[2][2], m2[2][2];
    #pragma unroll
    for (int rt = 0; rt < 2; ++rt)
        #pragma unroll
        for (int f = 0; f < 2; ++f) {
            m1[rt][f] = (f32x4){0.f,0.f,0.f,0.f};
            m2[rt][f] = (f32x4){0.f,0.f,0.f,0.f};
        }
    #pragma unroll 2
    for (int kk = 0; kk < KPAD / 32; ++kk) {
        const int kb = kk * 32 + lk * 8;
        bf16x8 a1[2], a2[2];
        #pragma unroll
        for (int rt = 0; rt < 2; ++rt) {
            a1[rt] = *(const bf16x8*)(Ab1 + (size_t)(n0 + rt * 16 + lr) * KPAD + kb);
            a2[rt] = *(const bf16x8*)(Ab2 + (size_t)(n0 + rt * 16 + lr) * KPAD + kb);
        }
        #pragma unroll
        for (int f = 0; f < 2; ++f) {
            bf16x8 bx = *(const bf16x8*)(xtB + (size_t)(b0 * HHv + w * 32 + f * 16 + lr) * KPAD + kb);
            #pragma unroll
            for (int rt = 0; rt < 2; ++rt) {
                m1[rt][f] = MFMA(a1[rt], bx, m1[rt][f]);
                m2[rt][f] = MFMA(a2[rt], bx, m2[rt][f]);
            }
        }
    }
    #pragma unroll
    for (int rt = 0; rt < 2; ++rt)
        #pragma unroll
        for (int f = 0; f < 2; ++f) {
            int colg = w * 32 + f * 16 + lr;
            int bl = colg >> 7, ch = colg & 127;
            #pragma unroll
            for (int i = 0; i < 4; ++i) {
                int r2 = bl * 32 + rt * 16 + lk * 4 + i;
                m1s[r2][ch] = f2bf(m1[rt][f][i]);
                m2s[r2][ch] = f2bf(m2[rt][f][i]);
            }
        }
    __syncthreads();

    // ---- GEMM2: d = 0.5*(m1@W1 + m2@W2), 64 rows x 128, K=128 ----
    f32x4 dacc[4];
    #pragma unroll
    for (int rt = 0; rt < 4; ++rt) dacc[rt] = (f32x4){0.f,0.f,0.f,0.f};
    #pragma unroll
    for (int kk = 0; kk < 4; ++kk) {
        const int kb = kk * 32 + lk * 8;
        bf16x8 b1 = *(const bf16x8*)(W1t + (size_t)(w * 16 + lr) * HHv + kb);
        bf16x8 b2 = *(const bf16x8*)(W2t + (size_t)(w * 16 + lr) * HHv + kb);
        #pragma unroll
        for (int rt = 0; rt < 4; ++rt) {
            bf16x8 a1x = *(const bf16x8*)&m1s[rt * 16 + lr][kb];
            bf16x8 a2x = *(const bf16x8*)&m2s[rt * 16 + lr][kb];
            dacc[rt] = MFMA(a1x, b1, dacc[rt]);
            dacc[rt] = MFMA(a2x, b2, dacc[rt]);
        }
    }
    __syncthreads();   // GEMM2 done reading m1s/m2s

    // ---- d -> m1s (x-buffer / projection input) ----
    {
        const int ch = w * 16 + lr;
        #pragma unroll
        for (int rt = 0; rt < 4; ++rt)
            #pragma unroll
            for (int i = 0; i < 4; ++i)
                m1s[rt * 16 + lk * 4 + i][ch] = f2bf(0.5f * dacc[rt][i]);
    }
    __syncthreads();

    if (WHICH == 1) {
        // ---- projection: out = d @ Wp_d + pfeat ----
        {
            int r2p = tid >> 3, sub = tid & 7;
            float a0 = 0.f, a1 = 0.f;
            #pragma unroll
            for (int q = 0; q < 16; ++q) {
                int k = sub * 16 + q;
                float v = bf2f(m1s[r2p][k]);
                a0 = fmaf(v, Wp[k * 2 + 0], a0);
                a1 = fmaf(v, Wp[k * 2 + 1], a1);
            }
            #pragma unroll
            for (int o = 4; o > 0; o >>= 1) {
                a0 += __shfl_down(a0, o, 8);
                a1 += __shfl_down(a1, o, 8);
            }
            if (sub == 0) {
                int n = n0 + (r2p & 31);
                float* os = (float*)&m1s[r2p][128];
                os[0] = a0 + pfeat[n * 2 + 0];
                os[1] = a1 + pfeat[n * 2 + 1];
            }
        }
        __syncthreads();
        // write out[t] + build xs in m2s[.][0..32) = [out(2) | aux(2) | 0...]
        if (tid < 128) {
            int r2 = tid >> 1, c = tid & 1;
            int n = n0 + (r2 & 31), b = b0 + (r2 >> 5);
            if (n < NN)
                out[(((size_t)n * BBv + b) * TTv + t) * ODDv + c] =
                    ((const float*)&m1s[r2][128])[c];
        }
        for (int e = tid; e < 64 * 32; e += 512) {
            int r2 = e >> 5, k = e & 31;
            int n = n0 + (r2 & 31), b = b0 + (r2 >> 5);
            int nc = (n > NN - 1) ? NN - 1 : n;
            ushort v;
            if (k < 2)      v = f2bf(((const float*)&m1s[r2][128])[k]);
            else if (k < 4) v = f2bf(label[(((size_t)nc * BBv + b) * TTv + t) * 4 + 2 + (k - 2)]);
            else            v = 0;
            m2s[r2][k] = v;
        }
        __syncthreads();
    }

    // ---- GRU: g = x@Wx + h@Wh + bias ----
    const int ch = w * 16 + lr;
    const float bzv = bias[ch], brv = bias[128 + ch], bcv = bias[256 + ch];
    f32x4 az[4], ar[4], agc[4], ahc[4];
    #pragma unroll
    for (int rt = 0; rt < 4; ++rt) {
        az[rt] = (f32x4){0.f,0.f,0.f,0.f};
        ar[rt] = (f32x4){0.f,0.f,0.f,0.f};
        agc[rt] = (f32x4){0.f,0.f,0.f,0.f};
        ahc[rt] = (f32x4){0.f,0.f,0.f,0.f};
    }
    #pragma unroll
    for (int kk = 0; kk < KXP / 32; ++kk) {
        const int kb = kk * 32 + lk * 8;
        bf16x8 bz = *(const bf16x8*)(Wxt + (size_t)ch * KXP + kb);
        bf16x8 br = *(const bf16x8*)(Wxt + (size_t)(128 + ch) * KXP + kb);
        bf16x8 bc = *(const bf16x8*)(Wxt + (size_t)(256 + ch) * KXP + kb);
        #pragma unroll
        for (int rt = 0; rt < 4; ++rt) {
            bf16x8 a;
            if (WHICH == 0) {
                if (kk < 4) a = *(const bf16x8*)&m1s[rt * 16 + lr][kb];
                else        a = *(const bf16x8*)&fs[(rt & 1) * 16 + lr][lk * 8];
            } else {
                if (kk == 0) a = *(const bf16x8*)&fs[(rt & 1) * 16 + lr][lk * 8];
                else         a = *(const bf16x8*)&m2s[rt * 16 + lr][lk * 8];
            }
            az[rt] = MFMA(a, bz, az[rt]);
            ar[rt] = MFMA(a, br, ar[rt]);
            agc[rt] = MFMA(a, bc, agc[rt]);
        }
    }
    #pragma unroll
    for (int kk = 0; kk < 4; ++kk) {
        const int kb = kk * 32 + lk * 8;
        bf16x8 bz = *(const bf16x8*)(Wht + (size_t)ch * HHv + kb);
        bf16x8 br = *(const bf16x8*)(Wht + (size_t)(128 + ch) * HHv + kb);
        bf16x8 bc = *(const bf16x8*)(Wht + (size_t)(256 + ch) * HHv + kb);
        #pragma unroll
        for (int rt = 0; rt < 4; ++rt) {
            bf16x8 a = *(const bf16x8*)&hs[rt * 16 + lr][kb];
            az[rt] = MFMA(a, bz, az[rt]);
            ar[rt] = MFMA(a, br, ar[rt]);
            ahc[rt] = MFMA(a, bc, ahc[rt]);
        }
    }

    if (WHICH == 1) __syncthreads();   // m2s xs-reads done before h-new overwrite

    // ---- gating -> m2s ----
    #pragma unroll
    for (int rt = 0; rt < 4; ++rt)
        #pragma unroll
        for (int i = 0; i < 4; ++i) {
            int r2 = rt * 16 + lk * 4 + i;
            float z  = sigmoidf_(az[rt][i] + bzv);
            float rr = sigmoidf_(ar[rt][i] + brv);
            float c  = tanhf(agc[rt][i] + bcv + rr * ahc[rt][i]);
            float hn = z * bf2f(hs[r2][ch]) + (1.f - z) * c;
            m2s[r2][ch] = f2bf(hn);
        }
    __syncthreads();

    // ---- write h-new transposed to xtO ----
    {
        int chg = tid >> 1, g = tid & 1;
        int bl = chg >> 7, chx = chg & 127;
        ushort8 v0, v1;
        #pragma unroll
        for (int k = 0; k < 8; ++k) v0[k] = m2s[bl * 32 + g * 16 + k][chx];
        #pragma unroll
        for (int k = 0; k < 8; ++k) v1[k] = m2s[bl * 32 + g * 16 + 8 + k][chx];
        ushort* dst = xtO + (size_t)((b0 + bl) * HHv + chx) * KPAD + n0 + g * 16;
        *(ushort8*)dst = v0;
        *(ushort8*)(dst + 8) = v1;
    }
}

// ---------------------------------------------------------------------------
extern "C" void kernel_launch(void* const* d_in, const int* in_sizes, int n_in,
                              void* d_out, int out_size, void* d_ws, size_t ws_size,
                              hipStream_t stream)
{
    const float* feature = (const float*)d_in[0];
    const float* label   = (const float*)d_in[1];
    const float* state0  = (const float*)d_in[2];
    const float* state1  = (const float*)d_in[3];
    const float* Wx0 = (const float*)d_in[4];
    const float* Wh0 = (const float*)d_in[5];
    const float* b0  = (const float*)d_in[6];
    const float* Wx1 = (const float*)d_in[7];
    const float* Wh1 = (const float*)d_in[8];
    const float* b1  = (const float*)d_in[9];
    const float* A01 = (const float*)d_in[10];
    const float* A02 = (const float*)d_in[11];
    const float* Wg01 = (const float*)d_in[12];
    const float* Wg02 = (const float*)d_in[13];
    const float* A11 = (const float*)d_in[14];
    const float* A12 = (const float*)d_in[15];
    const float* Wg11 = (const float*)d_in[16];
    const float* Wg12 = (const float*)d_in[17];
    const float* Wp  = (const float*)d_in[18];
    const float* bp  = (const float*)d_in[19];

    float* out = (float*)d_out;

    char* p = (char*)d_ws;
    auto alloc = [&](size_t bytes) {
        void* r = (void*)p; p += (bytes + 255) & ~(size_t)255; return r;
    };
    const size_t XTSZ = (size_t)BBv * HHv * KPAD;
    ushort* xt0[2] = { (ushort*)alloc(XTSZ * 2), (ushort*)alloc(XTSZ * 2) };
    ushort* xt1[2] = { (ushort*)alloc(XTSZ * 2), (ushort*)alloc(XTSZ * 2) };
    ushort* Ab01 = (ushort*)alloc((size_t)NPAD * KPAD * 2);
    ushort* Ab02 = (ushort*)alloc((size_t)NPAD * KPAD * 2);
    ushort* Ab11 = (ushort*)alloc((size_t)NPAD * KPAD * 2);
    ushort* Ab12 = (ushort*)alloc((size_t)NPAD * KPAD * 2);
    ushort* Wx0t = (ushort*)alloc((size_t)G3v * 64 * 2);
    ushort* Wh0t = (ushort*)alloc((size_t)G3v * HHv * 2);
    ushort* Wx1t = (ushort*)alloc((size_t)G3v * 160 * 2);
    ushort* Wh1t = (ushort*)alloc((size_t)G3v * HHv * 2);
    ushort* Wg01t = (ushort*)alloc((size_t)HHv * HHv * 2);
    ushort* Wg02t = (ushort*)alloc((size_t)HHv * HHv * 2);
    ushort* Wg11t = (ushort*)alloc((size_t)HHv * HHv * 2);
    ushort* Wg12t = (ushort*)alloc((size_t)HHv * HHv * 2);
    ushort* featb = (ushort*)alloc((size_t)NPAD * DFDv * 2);
    float*  gxf0 = (float*)alloc((size_t)NPAD * G3v * 4);
    float*  pfe  = (float*)alloc((size_t)NPAD * 2 * 4);

    auto cdiv = [](int a, int b) { return (a + b - 1) / b; };
    wtransx0_kernel<<<cdiv(G3v * 64, 256), 256, 0, stream>>>(Wx0, Wx0t);
    wtrans_kernel<<<cdiv(G3v * HHv, 256), 256, 0, stream>>>(Wh0, Wh0t, HHv, G3v, HHv);
    wtrans_kernel<<<cdiv(G3v * 160, 256), 256, 0, stream>>>(Wx1, Wx1t, 160, G3v, 160);
    wtrans_kernel<<<cdiv(G3v * HHv, 256), 256, 0, stream>>>(Wh1, Wh1t, HHv, G3v, HHv);
    wtrans_kernel<<<cdiv(HHv * HHv, 256), 256, 0, stream>>>(Wg01, Wg01t, HHv, HHv, HHv);
    wtrans_kernel<<<cdiv(HHv * HHv, 256), 256, 0, stream>>>(Wg02, Wg02t, HHv, HHv, HHv);
    wtrans_kernel<<<cdiv(HHv * HHv, 256), 256, 0, stream>>>(Wg11, Wg11t, HHv, HHv, HHv);
    wtrans_kernel<<<cdiv(HHv * HHv, 256), 256, 0, stream>>>(Wg12, Wg12t, HHv, HHv, HHv);
    aconv_kernel<<<cdiv(NPAD * KPAD, 256), 256, 0, stream>>>(A01, Ab01);
    aconv_kernel<<<cdiv(NPAD * KPAD, 256), 256, 0, stream>>>(A02, Ab02);
    aconv_kernel<<<cdiv(NPAD * KPAD, 256), 256, 0, stream>>>(A11, Ab11);
    aconv_kernel<<<cdiv(NPAD * KPAD, 256), 256, 0, stream>>>(A12, Ab12);
    fconv_kernel<<<cdiv(NPAD * DFDv, 256), 256, 0, stream>>>(feature, featb);
    gxf_kernel<<<NPAD, G3v, 0, stream>>>(Wx0, b0, feature, gxf0, 4);
    pfeat_kernel<<<NPAD, 64, 0, stream>>>(Wp, bp, feature, pfe);
    strans_kernel<<<cdiv((int)XTSZ, 256), 256, 0, stream>>>(state1, xt1[0]);

    // prologue: h0[0] = GRU0(data=0, state0) -> xt0[0]
    gru0_init<<<dim3(GX, BBv), 512, 0, stream>>>(state0, gxf0, Wh0t, xt0[0]);

    const dim3 grid(GX, GY);
    for (int t = 0; t < TTv; ++t) {
        // K_A: gconv0(h0[t]) + GRU1 -> h1[t]
        fused_step<0><<<grid, 512, 0, stream>>>(
            xt0[t & 1], xt1[t & 1], xt1[(t + 1) & 1],
            Ab01, Ab02, Wg01t, Wg02t, Wx1t, Wh1t, b1, featb,
            nullptr, nullptr, nullptr, nullptr, t);
        // K_B: gconv1(h1[t]) + proj(out[t]) + GRU0 -> h0[t+1]
        fused_step<1><<<grid, 512, 0, stream>>>(
            xt1[(t + 1) & 1], xt0[t & 1], xt0[(t + 1) & 1],
            Ab11, Ab12, Wg11t, Wg12t, Wx0t, Wh0t, b0, featb,
            label, Wp, pfe, out, t);
    }
}